// Round 19
// baseline (735.572 us; speedup 1.0000x reference)
//
#include <hip/hip_runtime.h>

#define D_MODEL   1024
#define D_HIDDEN  4096
#define N_EXPERTS 8
#define N_TOKENS  8192
#define NASSIGN   (N_TOKENS * 2)               // 16384
#define PADCAP    (NASSIGN + N_EXPERTS * 128)  // 17408
#define ROWT      (PADCAP / 128)               // 136 = 8*17

typedef unsigned short u16;
typedef __bf16 bf16x8 __attribute__((ext_vector_type(8)));
typedef float  f32x4  __attribute__((ext_vector_type(4)));

__device__ __forceinline__ u16 f2bf(float f) {
  union { float f; unsigned u; } c; c.f = f;
  unsigned u = c.u;
  u = (u + 0x7fffu + ((u >> 16) & 1u)) >> 16;   // RNE
  return (u16)u;
}

__device__ __forceinline__ float bf2f(u16 v) {
  union { unsigned u; float f; } c; c.u = ((unsigned)v) << 16;
  return c.f;
}

__device__ __forceinline__ void async16(const void* g, void* l) {
  __builtin_amdgcn_global_load_lds(
      (const __attribute__((address_space(1))) unsigned int*)g,
      (__attribute__((address_space(3))) unsigned int*)l, 16, 0, 0);
}

// ---------------- gating (vectorized, fused x->bf16): 4 tokens/block ----------------
__global__ __launch_bounds__(256) void gating_kernel(
    const float* __restrict__ x, const float* __restrict__ gw,
    const float* __restrict__ gb, int* __restrict__ counts,
    int* __restrict__ tok_idx, float* __restrict__ tok_w,
    u16* __restrict__ xb)
{
  const int n = blockIdx.x * 4 + (threadIdx.x >> 6);
  const int lane = threadIdx.x & 63;
  const float4* x4 = (const float4*)x;
  const float4* gw4 = (const float4*)gw;

  float acc[8] = {0.f,0.f,0.f,0.f,0.f,0.f,0.f,0.f};
  #pragma unroll
  for (int cch = 0; cch < 4; ++cch) {
    const int f4i = cch * 64 + lane;                 // float4 index in row, 0..255
    float4 xv = x4[(size_t)n * 256 + f4i];

    uint2 o;
    o.x = (unsigned)f2bf(xv.x) | ((unsigned)f2bf(xv.y) << 16);
    o.y = (unsigned)f2bf(xv.z) | ((unsigned)f2bf(xv.w) << 16);
    *(uint2*)&xb[(size_t)n * D_MODEL + f4i * 4] = o;

    float xr[4] = {xv.x, xv.y, xv.z, xv.w};
    #pragma unroll
    for (int r = 0; r < 4; ++r) {
      int row = f4i * 4 + r;
      float4 g0 = gw4[row * 2], g1 = gw4[row * 2 + 1];   // gw is 32KB, L1/L2-hot
      acc[0] += xr[r] * g0.x; acc[1] += xr[r] * g0.y;
      acc[2] += xr[r] * g0.z; acc[3] += xr[r] * g0.w;
      acc[4] += xr[r] * g1.x; acc[5] += xr[r] * g1.y;
      acc[6] += xr[r] * g1.z; acc[7] += xr[r] * g1.w;
    }
  }
  for (int off = 32; off; off >>= 1)
    #pragma unroll
    for (int e = 0; e < 8; ++e) acc[e] += __shfl_xor(acc[e], off, 64);
  if (lane == 0) {
    float l[8], p[8];
    float m = -1e30f;
    for (int e = 0; e < 8; ++e) { l[e] = acc[e] + gb[e]; m = fmaxf(m, l[e]); }
    float s = 0.f;
    for (int e = 0; e < 8; ++e) { p[e] = expf(l[e] - m); s += p[e]; }
    float inv = 1.f / s;
    for (int e = 0; e < 8; ++e) p[e] *= inv;
    int i0 = 0;
    for (int e = 1; e < 8; ++e) if (p[e] > p[i0]) i0 = e;          // ties -> lowest idx
    int i1 = (i0 == 0) ? 1 : 0;
    for (int e = 0; e < 8; ++e) if (e != i0 && p[e] > p[i1]) i1 = e;
    tok_idx[2 * n]     = i0;  tok_idx[2 * n + 1] = i1;
    tok_w[2 * n]       = p[i0]; tok_w[2 * n + 1] = p[i1];
    atomicAdd(&counts[i0], 1);
    atomicAdd(&counts[i1], 1);
  }
}

// ---------------- offsets + load-balancing loss ----------------
__global__ void finalize_routing(const int* __restrict__ counts,
                                 int* __restrict__ offsets,
                                 float* __restrict__ out_loss)
{
  int off = 0;
  for (int e = 0; e < 8; ++e) {
    offsets[e] = off;
    off += ((counts[e] + 127) >> 7) << 7;   // 128-align each expert segment
  }
  offsets[8] = off;
  float loss = 0.f;
  for (int e = 0; e < 8; ++e) {
    float f = (float)counts[e] * (1.f / (float)NASSIGN);
    loss += f * f;
  }
  *out_loss = loss;
}

// ---------------- scatter tokens to expert segments ----------------
__global__ __launch_bounds__(256) void scatter_kernel(
    const int* __restrict__ tok_idx, const float* __restrict__ tok_w,
    const int* __restrict__ offsets, int* __restrict__ cursors,
    int* __restrict__ assign_token, float* __restrict__ assign_w,
    int* __restrict__ tok_pos)
{
  const int n = blockIdx.x * 256 + threadIdx.x;
  #pragma unroll
  for (int k = 0; k < 2; ++k) {
    int e = tok_idx[n * 2 + k];
    int pos = offsets[e] + atomicAdd(&cursors[e], 1);
    assign_token[pos] = n;
    assign_w[pos] = tok_w[n * 2 + k];
    tok_pos[n * 2 + k] = pos;
  }
}

// ------- transpose+convert: [e][R][C] f32 -> [e][C][R] bf16. Tile 128r x 32c. -------
// Writes 256B-contiguous per output row (2 consecutive uint4 per thread).
// LDS bank check: read addr=(528s+33k+c) === (16s+k+c) mod 32 -> 4-way (1.58x, ok).
__global__ __launch_bounds__(256) void transpose_cvt_kernel(
    const float* __restrict__ in, u16* __restrict__ out, int R, int C)
{
  const int e = blockIdx.z;
  const int c0 = blockIdx.x * 32, r0 = blockIdx.y * 128;
  __shared__ float tile[128][33];
  const int tid = threadIdx.x;
  const float* ip = in + (size_t)e * R * C;
  u16* op = out + (size_t)e * R * C;
  const int rr = tid >> 3, c4 = (tid & 7) * 4;   // 32 rows/pass, 8 lanes x float4
  #pragma unroll
  for (int p = 0; p < 4; ++p) {
    int r = rr + p * 32;
    float4 v = *(const float4*)&ip[(size_t)(r0 + r) * C + c0 + c4];
    tile[r][c4 + 0] = v.x; tile[r][c4 + 1] = v.y;
    tile[r][c4 + 2] = v.z; tile[r][c4 + 3] = v.w;
  }
  __syncthreads();
  const int c = tid >> 3, s = tid & 7;           // out-row c (0..31), 32B segment s
  u16 buf[16];
  #pragma unroll
  for (int k = 0; k < 16; ++k) buf[k] = f2bf(tile[s * 16 + k][c]);
  *(uint4*)&op[(size_t)(c0 + c) * R + r0 + s * 16]     = *(const uint4*)&buf[0];
  *(uint4*)&op[(size_t)(c0 + c) * R + r0 + s * 16 + 8] = *(const uint4*)&buf[8];
}

// ===== GEMM1 (R18): 2-buffer staging (48KB -> 3 blocks/CU), two-pass Hs epilogue =====
__global__ __launch_bounds__(256, 2) void gemm1_kernel(
    const u16* __restrict__ xb, const u16* __restrict__ w1t,
    const float* __restrict__ b1, const int* __restrict__ assign_token,
    const int* __restrict__ offsets, u16* __restrict__ hbuf)
{
  const int rt = (blockIdx.x & 7) * 17 + (blockIdx.x >> 3);   // XCD-bijective
  const int ct = blockIdx.y;   // ct in [0,16)
  if (rt * 128 >= offsets[8]) return;
  int e = 0;
  while (offsets[e + 1] <= rt * 128) ++e;

  __shared__ __align__(16) u16 smem[24576];   // 48 KB

  const int tid = threadIdx.x;
  const int wave = tid >> 6, lane = tid & 63;

  const int ra0 = tid >> 2,         sa = tid & 3;
  const int ra1 = (tid + 256) >> 2;
  const int sga0 = sa ^ ((ra0 >> 1) & 3);
  const int sga1 = sa ^ ((ra1 >> 1) & 3);
  const long aBase0 = (long)assign_token[rt * 128 + ra0] * D_MODEL + sga0 * 8;
  const long aBase1 = (long)assign_token[rt * 128 + ra1] * D_MODEL + sga1 * 8;

  long bBase[4];
  #pragma unroll
  for (int k = 0; k < 4; ++k) {
    int c = tid + k * 256;
    int r = c >> 2, s = c & 3;
    int sg = s ^ ((r >> 1) & 3);
    bBase[k] = ((long)e * D_HIDDEN + ct * 256 + r) * D_MODEL + sg * 8;
  }

  const int wr = (wave >> 1) * 64;    // wave row base (0/64)
  const int wc = (wave & 1) * 128;    // wave col base (0/128)
  f32x4 acc[4][8];
  #pragma unroll
  for (int i = 0; i < 4; ++i)
    #pragma unroll
    for (int j = 0; j < 8; ++j) acc[i][j] = (f32x4){0.f, 0.f, 0.f, 0.f};

  int aoff[4], boff[8];   // region-relative
  #pragma unroll
  for (int i = 0; i < 4; ++i) {
    int row = wr + i * 16 + (lane & 15);
    aoff[i] = row * 32 + (((lane >> 4) ^ ((row >> 1) & 3)) * 8);
  }
  #pragma unroll
  for (int j = 0; j < 8; ++j) {
    int col = wc + j * 16 + (lane & 15);
    boff[j] = col * 32 + (((lane >> 4) ^ ((col >> 1) & 3)) * 8);
  }

  #define STAGE1(bi, k0) do { \
    u16* A_ = smem + (bi) * 12288; \
    u16* B_ = A_ + 4096; \
    async16(xb  + aBase0   + (k0), A_ + wave * 512); \
    async16(xb  + aBase1   + (k0), A_ + 2048 + wave * 512); \
    async16(w1t + bBase[0] + (k0), B_ + wave * 512); \
    async16(w1t + bBase[1] + (k0), B_ + 2048 + wave * 512); \
    async16(w1t + bBase[2] + (k0), B_ + 4096 + wave * 512); \
    async16(w1t + bBase[3] + (k0), B_ + 6144 + wave * 512); \
  } while (0)

  const int NT = D_MODEL / 32;   // 32
  STAGE1(0, 0);
  STAGE1(1, 32);
  for (int t = 0; t < NT; ++t) {
    const u16* A = smem + (t & 1) * 12288;
    const u16* B = A + 4096;
    if (t < NT - 1) asm volatile("s_waitcnt vmcnt(6)" ::: "memory");
    else            asm volatile("s_waitcnt vmcnt(0)" ::: "memory");
    __builtin_amdgcn_s_barrier();
    bf16x8 a[4], b[8];
    #pragma unroll
    for (int i = 0; i < 4; ++i) a[i] = *(const bf16x8*)&A[aoff[i]];
    #pragma unroll
    for (int j = 0; j < 8; ++j) b[j] = *(const bf16x8*)&B[boff[j]];
    // all waves' fragments in registers before anyone overwrites this buffer:
    asm volatile("s_waitcnt lgkmcnt(0)\n\ts_barrier" ::: "memory");
    if (t + 2 < NT) STAGE1(t & 1, (t + 2) * 32);
    __builtin_amdgcn_s_setprio(1);
    #pragma unroll
    for (int i = 0; i < 4; ++i)
      #pragma unroll
      for (int j = 0; j < 8; ++j)
        acc[i][j] = __builtin_amdgcn_mfma_f32_16x16x32_bf16(a[i], b[j], acc[i][j], 0, 0, 0);
    __builtin_amdgcn_s_setprio(0);
  }
  #undef STAGE1

  float bias[8];
  #pragma unroll
  for (int j = 0; j < 8; ++j)
    bias[j] = b1[(size_t)e * D_HIDDEN + ct * 256 + wc + j * 16 + (lane & 15)];

  __syncthreads();   // staging done before Hs overlay
  // Two-pass Hs: 128x128 bf16 (32KB) per half; half h written by waves with wc==h*128.
  u16* Hs = smem;
  #pragma unroll
  for (int half = 0; half < 2; ++half) {
    if ((wc >> 7) == half) {
      #pragma unroll
      for (int i = 0; i < 4; ++i)
        #pragma unroll
        for (int j = 0; j < 8; ++j)
          #pragma unroll
          for (int r = 0; r < 4; ++r) {
            int rl = wr + i * 16 + ((lane >> 4) * 4) + r;
            int cl = j * 16 + (lane & 15);          // 0..127 within half
            Hs[rl * 128 + cl] = f2bf(fmaxf(acc[i][j][r] + bias[j], 0.f));
          }
    }
    __syncthreads();
    #pragma unroll
    for (int t = 0; t < 8; ++t) {
      int cc = tid + t * 256;
      int row = cc >> 4, cs = cc & 15;
      *(uint4*)&hbuf[((size_t)(rt * 128 + row)) * D_HIDDEN + ct * 256 + half * 128 + cs * 8] =
          *(const uint4*)&Hs[row * 128 + cs * 8];
    }
    __syncthreads();
  }
}

// ========== GEMM2 (R17 proven): 2-buffer staging, 48KB LDS -> 3 blocks/CU ==========
template <bool EO>
__global__ __launch_bounds__(256, 2) void gemm2_kernel(
    const u16* __restrict__ hbuf, const u16* __restrict__ w2t,
    const float* __restrict__ b2, const int* __restrict__ assign_token,
    const float* __restrict__ assign_w, const int* __restrict__ offsets,
    void* __restrict__ dstv)   // EO ? u16* eo : float* out
{
  const int rt = (blockIdx.x & 7) * 17 + (blockIdx.x >> 3);   // XCD-bijective
  const int ct = blockIdx.y;   // ct in [0,4)
  if (rt * 128 >= offsets[8]) return;
  int e = 0;
  while (offsets[e + 1] <= rt * 128) ++e;

  __shared__ __align__(16) u16 smem[24576];
  __shared__ int tokS[128];
  __shared__ float wS[128];

  const int tid = threadIdx.x;
  const int wave = tid >> 6, lane = tid & 63;
  if (tid < 128) {
    tokS[tid] = assign_token[rt * 128 + tid];
    wS[tid] = assign_w[rt * 128 + tid];
  }

  const int ra0 = tid >> 2,         sa = tid & 3;
  const int ra1 = (tid + 256) >> 2;
  const int sga0 = sa ^ ((ra0 >> 1) & 3);
  const int sga1 = sa ^ ((ra1 >> 1) & 3);
  const long aBase0 = ((long)(rt * 128 + ra0)) * D_HIDDEN + sga0 * 8;
  const long aBase1 = ((long)(rt * 128 + ra1)) * D_HIDDEN + sga1 * 8;

  long bBase[4];
  #pragma unroll
  for (int k = 0; k < 4; ++k) {
    int c = tid + k * 256;
    int r = c >> 2, s = c & 3;
    int sg = s ^ ((r >> 1) & 3);
    bBase[k] = ((long)e * D_MODEL + ct * 256 + r) * D_HIDDEN + sg * 8;
  }

  const int wr = (wave >> 1) * 64;
  const int wc = (wave & 1) * 128;
  f32x4 acc[4][8];
  #pragma unroll
  for (int i = 0; i < 4; ++i)
    #pragma unroll
    for (int j = 0; j < 8; ++j) acc[i][j] = (f32x4){0.f, 0.f, 0.f, 0.f};

  int aoff[4], boff[8];   // region-relative offsets
  #pragma unroll
  for (int i = 0; i < 4; ++i) {
    int row = wr + i * 16 + (lane & 15);
    aoff[i] = row * 32 + (((lane >> 4) ^ ((row >> 1) & 3)) * 8);
  }
  #pragma unroll
  for (int j = 0; j < 8; ++j) {
    int col = wc + j * 16 + (lane & 15);
    boff[j] = col * 32 + (((lane >> 4) ^ ((col >> 1) & 3)) * 8);
  }

  #define STAGE2(bi, k0) do { \
    u16* A_ = smem + (bi) * 12288; \
    u16* B_ = A_ + 4096; \
    async16(hbuf + aBase0   + (k0), A_ + wave * 512); \
    async16(hbuf + aBase1   + (k0), A_ + 2048 + wave * 512); \
    async16(w2t  + bBase[0] + (k0), B_ + wave * 512); \
    async16(w2t  + bBase[1] + (k0), B_ + 2048 + wave * 512); \
    async16(w2t  + bBase[2] + (k0), B_ + 4096 + wave * 512); \
    async16(w2t  + bBase[3] + (k0), B_ + 6144 + wave * 512); \
  } while (0)

  const int NT = D_HIDDEN / 32;   // 128
  STAGE2(0, 0);
  STAGE2(1, 32);
  for (int t = 0; t < NT; ++t) {
    const u16* A = smem + (t & 1) * 12288;
    const u16* B = A + 4096;
    if (t < NT - 1) asm volatile("s_waitcnt vmcnt(6)" ::: "memory");
    else            asm volatile("s_waitcnt vmcnt(0)" ::: "memory");
    __builtin_amdgcn_s_barrier();
    bf16x8 a[4], b[8];
    #pragma unroll
    for (int i = 0; i < 4; ++i) a[i] = *(const bf16x8*)&A[aoff[i]];
    #pragma unroll
    for (int j = 0; j < 8; ++j) b[j] = *(const bf16x8*)&B[boff[j]];
    // all waves' fragments in registers before anyone overwrites this buffer:
    asm volatile("s_waitcnt lgkmcnt(0)\n\ts_barrier" ::: "memory");
    if (t + 2 < NT) STAGE2(t & 1, (t + 2) * 32);
    __builtin_amdgcn_s_setprio(1);
    #pragma unroll
    for (int i = 0; i < 4; ++i)
      #pragma unroll
      for (int j = 0; j < 8; ++j)
        acc[i][j] = __builtin_amdgcn_mfma_f32_16x16x32_bf16(a[i], b[j], acc[i][j], 0, 0, 0);
    __builtin_amdgcn_s_setprio(0);
  }
  #undef STAGE2

  float bias[8];
  #pragma unroll
  for (int j = 0; j < 8; ++j)
    bias[j] = b2[(size_t)e * D_MODEL + ct * 256 + wc + j * 16 + (lane & 15)];

  #pragma unroll
  for (int i = 0; i < 4; ++i)
    #pragma unroll
    for (int r = 0; r < 4; ++r) {
      int rl = wr + i * 16 + ((lane >> 4) * 4) + r;
      float wgt = wS[rl];
      if (EO) {
        u16* dst = (u16*)dstv;
        size_t row = (size_t)(rt * 128 + rl);
        #pragma unroll
        for (int j = 0; j < 8; ++j) {
          float v = (acc[i][j][r] + bias[j]) * wgt;
          dst[row * D_MODEL + ct * 256 + wc + j * 16 + (lane & 15)] = f2bf(v);
        }
      } else {
        float* dst = (float*)dstv;
        int tok = tokS[rl];
        #pragma unroll
        for (int j = 0; j < 8; ++j) {
          float v = (acc[i][j][r] + bias[j]) * wgt;
          atomicAdd(&dst[(size_t)tok * D_MODEL + ct * 256 + wc + j * 16 + (lane & 15)], v);
        }
      }
    }
}

// ---------------- combine: out[n] = eo_bf16[pos0] + eo_bf16[pos1] ----------------
__global__ __launch_bounds__(256) void combine_kernel(
    const u16* __restrict__ eo, const int* __restrict__ tok_pos,
    float* __restrict__ out)
{
  int idx = blockIdx.x * 256 + threadIdx.x;   // 4 values per thread
  int n = idx >> 8;                           // 256 chunks per token
  int c = (idx & 255) * 4;
  int p0 = tok_pos[2 * n], p1 = tok_pos[2 * n + 1];
  uint2 ua = *(const uint2*)&eo[(size_t)p0 * D_MODEL + c];
  uint2 ub = *(const uint2*)&eo[(size_t)p1 * D_MODEL + c];
  float4 o;
  o.x = bf2f((u16)(ua.x & 0xffff))  + bf2f((u16)(ub.x & 0xffff));
  o.y = bf2f((u16)(ua.x >> 16))     + bf2f((u16)(ub.x >> 16));
  o.z = bf2f((u16)(ua.y & 0xffff))  + bf2f((u16)(ub.y & 0xffff));
  o.w = bf2f((u16)(ua.y >> 16))     + bf2f((u16)(ub.y >> 16));
  *(float4*)&out[(size_t)n * D_MODEL + c] = o;
}

// ---------------- fallback (tiny ws): naive fp32 per-assignment ----------------
__global__ __launch_bounds__(256) void moe_fallback_kernel(
    const float* __restrict__ x, const float* __restrict__ w1,
    const float* __restrict__ b1, const float* __restrict__ w2,
    const float* __restrict__ b2, const int* __restrict__ tok_idx,
    const float* __restrict__ tok_w, float* __restrict__ out)
{
  const int a = blockIdx.x;
  const int n = a >> 1, slot = a & 1;
  const int e = tok_idx[n * 2 + slot];
  const float wgt = tok_w[n * 2 + slot];
  __shared__ float xs[D_MODEL];
  __shared__ float hs[D_HIDDEN];
  const int tid = threadIdx.x;
  for (int d = tid; d < D_MODEL; d += 256) xs[d] = x[(size_t)n * D_MODEL + d];
  __syncthreads();
  for (int h = tid; h < D_HIDDEN; h += 256) {
    float acc = b1[(size_t)e * D_HIDDEN + h];
    for (int d = 0; d < D_MODEL; ++d)
      acc += xs[d] * w1[((size_t)e * D_MODEL + d) * D_HIDDEN + h];
    hs[h] = fmaxf(acc, 0.f);
  }
  __syncthreads();
  for (int d = tid; d < D_MODEL; d += 256) {
    float acc = b2[(size_t)e * D_MODEL + d];
    for (int h = 0; h < D_HIDDEN; ++h)
      acc += hs[h] * w2[((size_t)e * D_HIDDEN + h) * D_MODEL + d];
    atomicAdd(&out[(size_t)n * D_MODEL + d], wgt * acc);
  }
}

extern "C" void kernel_launch(void* const* d_in, const int* in_sizes, int n_in,
                              void* d_out, int out_size, void* d_ws, size_t ws_size,
                              hipStream_t stream) {
  const float* x      = (const float*)d_in[0];
  const float* gate_w = (const float*)d_in[1];
  const float* gate_b = (const float*)d_in[2];
  const float* w1     = (const float*)d_in[3];
  const float* b1     = (const float*)d_in[4];
  const float* w2     = (const float*)d_in[5];
  const float* b2     = (const float*)d_in[6];
  float* out = (float*)d_out;

  char* ws = (char*)d_ws;
  int*   counts       = (int*)(ws + 0);
  int*   cursors      = (int*)(ws + 32);
  int*   offsets      = (int*)(ws + 64);
  int*   tok_idx      = (int*)(ws + 256);       // 64 KB
  float* tok_w        = (float*)(ws + 65792);   // 64 KB
  int*   tok_pos      = (int*)(ws + 131328);    // 64 KB
  int*   assign_token = (int*)(ws + 196864);    // 68 KB
  float* assign_w     = (float*)(ws + 266496);  // 68 KB
  const size_t X0 = 336128;
  u16* xb   = (u16*)(ws + X0);
  u16* w1t  = (u16*)(ws + X0 + 16777216);
  u16* w2t  = (u16*)(ws + X0);                  // aliases xb+w1t (dead after GEMM1)
  u16* hbuf = (u16*)(ws + X0 + 83886080);
  u16* eo   = (u16*)(ws + X0 + 226492416ull);   // [PADCAP][1024] bf16 (no overlap)
  const size_t REQ_FAST = X0 + 226492416ull;                 // ~216 MiB
  const size_t REQ_EO   = REQ_FAST + 35651584ull;            // ~250 MiB

  const bool fast = (ws_size >= REQ_FAST);
  const bool eoPath = (ws_size >= REQ_EO);

  // zero routing scratch (incl. pad entries of assign_* -> token 0, weight 0)
  hipMemsetAsync(ws, 0, fast ? X0 : 336128, stream);
  if (!eoPath) {
    hipMemsetAsync(d_out, 0, (size_t)out_size * sizeof(float), stream);
  }

  gating_kernel<<<N_TOKENS / 4, 256, 0, stream>>>(x, gate_w, gate_b, counts,
                                                  tok_idx, tok_w, xb);
  finalize_routing<<<1, 1, 0, stream>>>(counts, offsets, out + (out_size - 1));

  if (fast) {
    scatter_kernel<<<N_TOKENS / 256, 256, 0, stream>>>(tok_idx, tok_w, offsets, cursors,
                                                       assign_token, assign_w, tok_pos);
    transpose_cvt_kernel<<<dim3(D_HIDDEN / 32, D_MODEL / 128, N_EXPERTS), 256, 0, stream>>>(
        w1, w1t, D_MODEL, D_HIDDEN);
    gemm1_kernel<<<dim3(ROWT, D_HIDDEN / 256), 256, 0, stream>>>(
        xb, w1t, b1, assign_token, offsets, hbuf);
    transpose_cvt_kernel<<<dim3(D_MODEL / 32, D_HIDDEN / 128, N_EXPERTS), 256, 0, stream>>>(
        w2, w2t, D_HIDDEN, D_MODEL);
    if (eoPath) {
      gemm2_kernel<true><<<dim3(ROWT, D_MODEL / 256), 256, 0, stream>>>(
          hbuf, w2t, b2, assign_token, assign_w, offsets, eo);
      combine_kernel<<<(N_TOKENS * D_MODEL) / 1024, 256, 0, stream>>>(eo, tok_pos, out);
    } else {
      gemm2_kernel<false><<<dim3(ROWT, D_MODEL / 256), 256, 0, stream>>>(
          hbuf, w2t, b2, assign_token, assign_w, offsets, out);
    }
  } else {
    moe_fallback_kernel<<<NASSIGN, 256, 0, stream>>>(x, w1, b1, w2, b2, tok_idx, tok_w, out);
  }
}

// Round 20
// 726.644 us; speedup vs baseline: 1.0123x; 1.0123x over previous
//
#include <hip/hip_runtime.h>

#define D_MODEL   1024
#define D_HIDDEN  4096
#define N_EXPERTS 8
#define N_TOKENS  8192
#define NASSIGN   (N_TOKENS * 2)               // 16384
#define PADCAP    (NASSIGN + N_EXPERTS * 128)  // 17408
#define ROWT      (PADCAP / 128)               // 136 = 8*17

typedef unsigned short u16;
typedef __bf16 bf16x8 __attribute__((ext_vector_type(8)));
typedef float  f32x4  __attribute__((ext_vector_type(4)));

__device__ __forceinline__ u16 f2bf(float f) {
  union { float f; unsigned u; } c; c.f = f;
  unsigned u = c.u;
  u = (u + 0x7fffu + ((u >> 16) & 1u)) >> 16;   // RNE
  return (u16)u;
}

__device__ __forceinline__ float bf2f(u16 v) {
  union { unsigned u; float f; } c; c.u = ((unsigned)v) << 16;
  return c.f;
}

__device__ __forceinline__ void async16(const void* g, void* l) {
  __builtin_amdgcn_global_load_lds(
      (const __attribute__((address_space(1))) unsigned int*)g,
      (__attribute__((address_space(3))) unsigned int*)l, 16, 0, 0);
}

// ---------------- gating (vectorized, fused x->bf16): 4 tokens/block ----------------
__global__ __launch_bounds__(256) void gating_kernel(
    const float* __restrict__ x, const float* __restrict__ gw,
    const float* __restrict__ gb, int* __restrict__ counts,
    int* __restrict__ tok_idx, float* __restrict__ tok_w,
    u16* __restrict__ xb)
{
  const int n = blockIdx.x * 4 + (threadIdx.x >> 6);
  const int lane = threadIdx.x & 63;
  const float4* x4 = (const float4*)x;
  const float4* gw4 = (const float4*)gw;

  float acc[8] = {0.f,0.f,0.f,0.f,0.f,0.f,0.f,0.f};
  #pragma unroll
  for (int cch = 0; cch < 4; ++cch) {
    const int f4i = cch * 64 + lane;                 // float4 index in row, 0..255
    float4 xv = x4[(size_t)n * 256 + f4i];

    uint2 o;
    o.x = (unsigned)f2bf(xv.x) | ((unsigned)f2bf(xv.y) << 16);
    o.y = (unsigned)f2bf(xv.z) | ((unsigned)f2bf(xv.w) << 16);
    *(uint2*)&xb[(size_t)n * D_MODEL + f4i * 4] = o;

    float xr[4] = {xv.x, xv.y, xv.z, xv.w};
    #pragma unroll
    for (int r = 0; r < 4; ++r) {
      int row = f4i * 4 + r;
      float4 g0 = gw4[row * 2], g1 = gw4[row * 2 + 1];   // gw is 32KB, L1/L2-hot
      acc[0] += xr[r] * g0.x; acc[1] += xr[r] * g0.y;
      acc[2] += xr[r] * g0.z; acc[3] += xr[r] * g0.w;
      acc[4] += xr[r] * g1.x; acc[5] += xr[r] * g1.y;
      acc[6] += xr[r] * g1.z; acc[7] += xr[r] * g1.w;
    }
  }
  for (int off = 32; off; off >>= 1)
    #pragma unroll
    for (int e = 0; e < 8; ++e) acc[e] += __shfl_xor(acc[e], off, 64);
  if (lane == 0) {
    float l[8], p[8];
    float m = -1e30f;
    for (int e = 0; e < 8; ++e) { l[e] = acc[e] + gb[e]; m = fmaxf(m, l[e]); }
    float s = 0.f;
    for (int e = 0; e < 8; ++e) { p[e] = expf(l[e] - m); s += p[e]; }
    float inv = 1.f / s;
    for (int e = 0; e < 8; ++e) p[e] *= inv;
    int i0 = 0;
    for (int e = 1; e < 8; ++e) if (p[e] > p[i0]) i0 = e;          // ties -> lowest idx
    int i1 = (i0 == 0) ? 1 : 0;
    for (int e = 0; e < 8; ++e) if (e != i0 && p[e] > p[i1]) i1 = e;
    tok_idx[2 * n]     = i0;  tok_idx[2 * n + 1] = i1;
    tok_w[2 * n]       = p[i0]; tok_w[2 * n + 1] = p[i1];
    atomicAdd(&counts[i0], 1);
    atomicAdd(&counts[i1], 1);
  }
}

// ---------------- offsets + load-balancing loss ----------------
__global__ void finalize_routing(const int* __restrict__ counts,
                                 int* __restrict__ offsets,
                                 float* __restrict__ out_loss)
{
  int off = 0;
  for (int e = 0; e < 8; ++e) {
    offsets[e] = off;
    off += ((counts[e] + 127) >> 7) << 7;   // 128-align each expert segment
  }
  offsets[8] = off;
  float loss = 0.f;
  for (int e = 0; e < 8; ++e) {
    float f = (float)counts[e] * (1.f / (float)NASSIGN);
    loss += f * f;
  }
  *out_loss = loss;
}

// ---------------- scatter tokens to expert segments ----------------
__global__ __launch_bounds__(256) void scatter_kernel(
    const int* __restrict__ tok_idx, const float* __restrict__ tok_w,
    const int* __restrict__ offsets, int* __restrict__ cursors,
    int* __restrict__ assign_token, float* __restrict__ assign_w,
    int* __restrict__ tok_pos)
{
  const int n = blockIdx.x * 256 + threadIdx.x;
  #pragma unroll
  for (int k = 0; k < 2; ++k) {
    int e = tok_idx[n * 2 + k];
    int pos = offsets[e] + atomicAdd(&cursors[e], 1);
    assign_token[pos] = n;
    assign_w[pos] = tok_w[n * 2 + k];
    tok_pos[n * 2 + k] = pos;
  }
}

// ---------------- transpose+convert (proven 64x65): [e][R][C] f32 -> [e][C][R] bf16 ------
__global__ __launch_bounds__(256) void transpose_cvt_kernel(
    const float* __restrict__ in, u16* __restrict__ out, int R, int C)
{
  const int e = blockIdx.z;
  const int c0 = blockIdx.x * 64, r0 = blockIdx.y * 64;
  __shared__ float tile[64][65];
  const int tx = threadIdx.x & 15;        // 16 x float4 = 64 cols
  const int ty = threadIdx.x >> 4;        // 16 rows/pass
  const float* ip = in + (size_t)e * R * C;
  u16* op = out + (size_t)e * R * C;
  #pragma unroll
  for (int i = 0; i < 4; ++i) {
    int r = ty + i * 16;
    float4 v = *(const float4*)&ip[(size_t)(r0 + r) * C + c0 + tx * 4];
    tile[r][tx * 4 + 0] = v.x; tile[r][tx * 4 + 1] = v.y;
    tile[r][tx * 4 + 2] = v.z; tile[r][tx * 4 + 3] = v.w;
  }
  __syncthreads();
  const int c = threadIdx.x >> 2, seg = threadIdx.x & 3;   // out-row c, 32B segment
  u16 buf[16];
  #pragma unroll
  for (int k = 0; k < 16; ++k) buf[k] = f2bf(tile[seg * 16 + k][c]);
  *(uint4*)&op[(size_t)(c0 + c) * R + r0 + seg * 16]     = *(const uint4*)&buf[0];
  *(uint4*)&op[(size_t)(c0 + c) * R + r0 + seg * 16 + 8] = *(const uint4*)&buf[8];
}

// ================== GEMM1 (best measured: 3 cyclic bufs, 72KB) ==================
// BM=128, BN=256, BK=32. 4 waves, wave-tile 64x128. Counted vmcnt(6), raw s_barrier.
// XCD-bijective rt swizzle (136 = 8*17).
__global__ __launch_bounds__(256, 2) void gemm1_kernel(
    const u16* __restrict__ xb, const u16* __restrict__ w1t,
    const float* __restrict__ b1, const int* __restrict__ assign_token,
    const int* __restrict__ offsets, u16* __restrict__ hbuf)
{
  const int rt = (blockIdx.x & 7) * 17 + (blockIdx.x >> 3);   // XCD-bijective
  const int ct = blockIdx.y;   // ct in [0,16)
  if (rt * 128 >= offsets[8]) return;
  int e = 0;
  while (offsets[e + 1] <= rt * 128) ++e;

  __shared__ __align__(16) u16 smem[36864];
  u16* Asm = smem;            // [0, 12288)
  u16* Bsm = smem + 12288;    // [12288, 36864)

  const int tid = threadIdx.x;
  const int wave = tid >> 6, lane = tid & 63;

  const int ra0 = tid >> 2,         sa = tid & 3;
  const int ra1 = (tid + 256) >> 2;
  const int sga0 = sa ^ ((ra0 >> 1) & 3);
  const int sga1 = sa ^ ((ra1 >> 1) & 3);
  const long aBase0 = (long)assign_token[rt * 128 + ra0] * D_MODEL + sga0 * 8;
  const long aBase1 = (long)assign_token[rt * 128 + ra1] * D_MODEL + sga1 * 8;

  long bBase[4];
  #pragma unroll
  for (int k = 0; k < 4; ++k) {
    int c = tid + k * 256;
    int r = c >> 2, s = c & 3;
    int sg = s ^ ((r >> 1) & 3);
    bBase[k] = ((long)e * D_HIDDEN + ct * 256 + r) * D_MODEL + sg * 8;
  }

  const int wr = (wave >> 1) * 64;    // wave row base (0/64)
  const int wc = (wave & 1) * 128;    // wave col base (0/128)
  f32x4 acc[4][8];
  #pragma unroll
  for (int i = 0; i < 4; ++i)
    #pragma unroll
    for (int j = 0; j < 8; ++j) acc[i][j] = (f32x4){0.f, 0.f, 0.f, 0.f};

  int aoff[4], boff[8];
  #pragma unroll
  for (int i = 0; i < 4; ++i) {
    int row = wr + i * 16 + (lane & 15);
    aoff[i] = row * 32 + (((lane >> 4) ^ ((row >> 1) & 3)) * 8);
  }
  #pragma unroll
  for (int j = 0; j < 8; ++j) {
    int col = wc + j * 16 + (lane & 15);
    boff[j] = col * 32 + (((lane >> 4) ^ ((col >> 1) & 3)) * 8);
  }

  #define STAGE1(bi, k0) do { \
    u16* A_ = Asm + (bi) * 4096; \
    u16* B_ = Bsm + (bi) * 8192; \
    async16(xb  + aBase0   + (k0), A_ + wave * 512); \
    async16(xb  + aBase1   + (k0), A_ + 2048 + wave * 512); \
    async16(w1t + bBase[0] + (k0), B_ + wave * 512); \
    async16(w1t + bBase[1] + (k0), B_ + 2048 + wave * 512); \
    async16(w1t + bBase[2] + (k0), B_ + 4096 + wave * 512); \
    async16(w1t + bBase[3] + (k0), B_ + 6144 + wave * 512); \
  } while (0)

  const int NT = D_MODEL / 32;   // 32
  STAGE1(0, 0);
  STAGE1(1, 32);
  int bi = 0;
  for (int t = 0; t < NT; ++t) {
    if (t < NT - 1) asm volatile("s_waitcnt vmcnt(6)" ::: "memory");
    else            asm volatile("s_waitcnt vmcnt(0)" ::: "memory");
    __builtin_amdgcn_s_barrier();
    const u16* A = Asm + bi * 4096;
    const u16* B = Bsm + bi * 8192;
    bf16x8 a[4], b[8];
    #pragma unroll
    for (int i = 0; i < 4; ++i) a[i] = *(const bf16x8*)&A[aoff[i]];
    #pragma unroll
    for (int j = 0; j < 8; ++j) b[j] = *(const bf16x8*)&B[boff[j]];
    __builtin_amdgcn_s_setprio(1);
    #pragma unroll
    for (int i = 0; i < 4; ++i)
      #pragma unroll
      for (int j = 0; j < 8; ++j)
        acc[i][j] = __builtin_amdgcn_mfma_f32_16x16x32_bf16(a[i], b[j], acc[i][j], 0, 0, 0);
    __builtin_amdgcn_s_setprio(0);
    if (t + 2 < NT) {
      int nb = bi + 2; if (nb >= 3) nb -= 3;
      STAGE1(nb, (t + 2) * 32);
    }
    ++bi; if (bi == 3) bi = 0;
  }
  #undef STAGE1

  float bias[8];
  #pragma unroll
  for (int j = 0; j < 8; ++j)
    bias[j] = b1[(size_t)e * D_HIDDEN + ct * 256 + wc + j * 16 + (lane & 15)];

  __syncthreads();   // all LDS reads of staging bufs done before Hs overlay
  u16* Hs = smem;
  #pragma unroll
  for (int i = 0; i < 4; ++i)
    #pragma unroll
    for (int j = 0; j < 8; ++j)
      #pragma unroll
      for (int r = 0; r < 4; ++r) {
        int rl = wr + i * 16 + ((lane >> 4) * 4) + r;
        int cl = wc + j * 16 + (lane & 15);
        Hs[rl * 256 + cl] = f2bf(fmaxf(acc[i][j][r] + bias[j], 0.f));
      }
  __syncthreads();
  #pragma unroll
  for (int t = 0; t < 16; ++t) {
    int cc = tid + t * 256;
    int row = cc >> 5, cs = cc & 31;
    *(uint4*)&hbuf[((size_t)(rt * 128 + row)) * D_HIDDEN + ct * 256 + cs * 8] =
        *(const uint4*)&Hs[row * 256 + cs * 8];
  }
}

// ========== GEMM2 (best measured): 2-buffer staging, 48KB LDS -> 3 blocks/CU ==========
// __launch_bounds__(256, 2): min-waves floor of 3 would cap VGPRs (84) and spill
// acc[4][8] to scratch (R16: 1 GB writes). LDS (49KB) alone gives 3 resident blocks/CU.
template <bool EO>
__global__ __launch_bounds__(256, 2) void gemm2_kernel(
    const u16* __restrict__ hbuf, const u16* __restrict__ w2t,
    const float* __restrict__ b2, const int* __restrict__ assign_token,
    const float* __restrict__ assign_w, const int* __restrict__ offsets,
    void* __restrict__ dstv)   // EO ? u16* eo : float* out
{
  const int rt = (blockIdx.x & 7) * 17 + (blockIdx.x >> 3);   // XCD-bijective
  const int ct = blockIdx.y;   // ct in [0,4)
  if (rt * 128 >= offsets[8]) return;
  int e = 0;
  while (offsets[e + 1] <= rt * 128) ++e;

  // buf b: A at b*12288, B at b*12288+4096 (u16 units). 2 bufs = 48KB.
  __shared__ __align__(16) u16 smem[24576];
  __shared__ int tokS[128];
  __shared__ float wS[128];

  const int tid = threadIdx.x;
  const int wave = tid >> 6, lane = tid & 63;
  if (tid < 128) {
    tokS[tid] = assign_token[rt * 128 + tid];
    wS[tid] = assign_w[rt * 128 + tid];
  }

  const int ra0 = tid >> 2,         sa = tid & 3;
  const int ra1 = (tid + 256) >> 2;
  const int sga0 = sa ^ ((ra0 >> 1) & 3);
  const int sga1 = sa ^ ((ra1 >> 1) & 3);
  const long aBase0 = ((long)(rt * 128 + ra0)) * D_HIDDEN + sga0 * 8;
  const long aBase1 = ((long)(rt * 128 + ra1)) * D_HIDDEN + sga1 * 8;

  long bBase[4];
  #pragma unroll
  for (int k = 0; k < 4; ++k) {
    int c = tid + k * 256;
    int r = c >> 2, s = c & 3;
    int sg = s ^ ((r >> 1) & 3);
    bBase[k] = ((long)e * D_MODEL + ct * 256 + r) * D_HIDDEN + sg * 8;
  }

  const int wr = (wave >> 1) * 64;
  const int wc = (wave & 1) * 128;
  f32x4 acc[4][8];
  #pragma unroll
  for (int i = 0; i < 4; ++i)
    #pragma unroll
    for (int j = 0; j < 8; ++j) acc[i][j] = (f32x4){0.f, 0.f, 0.f, 0.f};

  int aoff[4], boff[8];   // region-relative offsets
  #pragma unroll
  for (int i = 0; i < 4; ++i) {
    int row = wr + i * 16 + (lane & 15);
    aoff[i] = row * 32 + (((lane >> 4) ^ ((row >> 1) & 3)) * 8);
  }
  #pragma unroll
  for (int j = 0; j < 8; ++j) {
    int col = wc + j * 16 + (lane & 15);
    boff[j] = col * 32 + (((lane >> 4) ^ ((col >> 1) & 3)) * 8);
  }

  #define STAGE2(bi, k0) do { \
    u16* A_ = smem + (bi) * 12288; \
    u16* B_ = A_ + 4096; \
    async16(hbuf + aBase0   + (k0), A_ + wave * 512); \
    async16(hbuf + aBase1   + (k0), A_ + 2048 + wave * 512); \
    async16(w2t  + bBase[0] + (k0), B_ + wave * 512); \
    async16(w2t  + bBase[1] + (k0), B_ + 2048 + wave * 512); \
    async16(w2t  + bBase[2] + (k0), B_ + 4096 + wave * 512); \
    async16(w2t  + bBase[3] + (k0), B_ + 6144 + wave * 512); \
  } while (0)

  const int NT = D_HIDDEN / 32;   // 128
  STAGE2(0, 0);
  STAGE2(1, 32);
  for (int t = 0; t < NT; ++t) {
    const u16* A = smem + (t & 1) * 12288;
    const u16* B = A + 4096;
    if (t < NT - 1) asm volatile("s_waitcnt vmcnt(6)" ::: "memory");
    else            asm volatile("s_waitcnt vmcnt(0)" ::: "memory");
    __builtin_amdgcn_s_barrier();
    bf16x8 a[4], b[8];
    #pragma unroll
    for (int i = 0; i < 4; ++i) a[i] = *(const bf16x8*)&A[aoff[i]];
    #pragma unroll
    for (int j = 0; j < 8; ++j) b[j] = *(const bf16x8*)&B[boff[j]];
    // all waves' fragments in registers before anyone overwrites this buffer:
    asm volatile("s_waitcnt lgkmcnt(0)\n\ts_barrier" ::: "memory");
    if (t + 2 < NT) STAGE2(t & 1, (t + 2) * 32);
    __builtin_amdgcn_s_setprio(1);
    #pragma unroll
    for (int i = 0; i < 4; ++i)
      #pragma unroll
      for (int j = 0; j < 8; ++j)
        acc[i][j] = __builtin_amdgcn_mfma_f32_16x16x32_bf16(a[i], b[j], acc[i][j], 0, 0, 0);
    __builtin_amdgcn_s_setprio(0);
  }
  #undef STAGE2

  float bias[8];
  #pragma unroll
  for (int j = 0; j < 8; ++j)
    bias[j] = b2[(size_t)e * D_MODEL + ct * 256 + wc + j * 16 + (lane & 15)];

  #pragma unroll
  for (int i = 0; i < 4; ++i)
    #pragma unroll
    for (int r = 0; r < 4; ++r) {
      int rl = wr + i * 16 + ((lane >> 4) * 4) + r;
      float wgt = wS[rl];
      if (EO) {
        u16* dst = (u16*)dstv;
        size_t row = (size_t)(rt * 128 + rl);
        #pragma unroll
        for (int j = 0; j < 8; ++j) {
          float v = (acc[i][j][r] + bias[j]) * wgt;
          dst[row * D_MODEL + ct * 256 + wc + j * 16 + (lane & 15)] = f2bf(v);
        }
      } else {
        float* dst = (float*)dstv;
        int tok = tokS[rl];
        #pragma unroll
        for (int j = 0; j < 8; ++j) {
          float v = (acc[i][j][r] + bias[j]) * wgt;
          atomicAdd(&dst[(size_t)tok * D_MODEL + ct * 256 + wc + j * 16 + (lane & 15)], v);
        }
      }
    }
}

// ---------------- combine: out[n] = eo_bf16[pos0] + eo_bf16[pos1] ----------------
__global__ __launch_bounds__(256) void combine_kernel(
    const u16* __restrict__ eo, const int* __restrict__ tok_pos,
    float* __restrict__ out)
{
  int idx = blockIdx.x * 256 + threadIdx.x;   // 4 values per thread
  int n = idx >> 8;                           // 256 chunks per token
  int c = (idx & 255) * 4;
  int p0 = tok_pos[2 * n], p1 = tok_pos[2 * n + 1];
  uint2 ua = *(const uint2*)&eo[(size_t)p0 * D_MODEL + c];
  uint2 ub = *(const uint2*)&eo[(size_t)p1 * D_MODEL + c];
  float4 o;
  o.x = bf2f((u16)(ua.x & 0xffff))  + bf2f((u16)(ub.x & 0xffff));
  o.y = bf2f((u16)(ua.x >> 16))     + bf2f((u16)(ub.x >> 16));
  o.z = bf2f((u16)(ua.y & 0xffff))  + bf2f((u16)(ub.y & 0xffff));
  o.w = bf2f((u16)(ua.y >> 16))     + bf2f((u16)(ub.y >> 16));
  *(float4*)&out[(size_t)n * D_MODEL + c] = o;
}

// ---------------- fallback (tiny ws): naive fp32 per-assignment ----------------
__global__ __launch_bounds__(256) void moe_fallback_kernel(
    const float* __restrict__ x, const float* __restrict__ w1,
    const float* __restrict__ b1, const float* __restrict__ w2,
    const float* __restrict__ b2, const int* __restrict__ tok_idx,
    const float* __restrict__ tok_w, float* __restrict__ out)
{
  const int a = blockIdx.x;
  const int n = a >> 1, slot = a & 1;
  const int e = tok_idx[n * 2 + slot];
  const float wgt = tok_w[n * 2 + slot];
  __shared__ float xs[D_MODEL];
  __shared__ float hs[D_HIDDEN];
  const int tid = threadIdx.x;
  for (int d = tid; d < D_MODEL; d += 256) xs[d] = x[(size_t)n * D_MODEL + d];
  __syncthreads();
  for (int h = tid; h < D_HIDDEN; h += 256) {
    float acc = b1[(size_t)e * D_HIDDEN + h];
    for (int d = 0; d < D_MODEL; ++d)
      acc += xs[d] * w1[((size_t)e * D_MODEL + d) * D_HIDDEN + h];
    hs[h] = fmaxf(acc, 0.f);
  }
  __syncthreads();
  for (int d = tid; d < D_MODEL; d += 256) {
    float acc = b2[(size_t)e * D_MODEL + d];
    for (int h = 0; h < D_HIDDEN; ++h)
      acc += hs[h] * w2[((size_t)e * D_HIDDEN + h) * D_MODEL + d];
    atomicAdd(&out[(size_t)n * D_MODEL + d], wgt * acc);
  }
}

extern "C" void kernel_launch(void* const* d_in, const int* in_sizes, int n_in,
                              void* d_out, int out_size, void* d_ws, size_t ws_size,
                              hipStream_t stream) {
  const float* x      = (const float*)d_in[0];
  const float* gate_w = (const float*)d_in[1];
  const float* gate_b = (const float*)d_in[2];
  const float* w1     = (const float*)d_in[3];
  const float* b1     = (const float*)d_in[4];
  const float* w2     = (const float*)d_in[5];
  const float* b2     = (const float*)d_in[6];
  float* out = (float*)d_out;

  char* ws = (char*)d_ws;
  int*   counts       = (int*)(ws + 0);
  int*   cursors      = (int*)(ws + 32);
  int*   offsets      = (int*)(ws + 64);
  int*   tok_idx      = (int*)(ws + 256);       // 64 KB
  float* tok_w        = (float*)(ws + 65792);   // 64 KB
  int*   tok_pos      = (int*)(ws + 131328);    // 64 KB
  int*   assign_token = (int*)(ws + 196864);    // 68 KB
  float* assign_w     = (float*)(ws + 266496);  // 68 KB
  const size_t X0 = 336128;
  u16* xb   = (u16*)(ws + X0);
  u16* w1t  = (u16*)(ws + X0 + 16777216);
  u16* w2t  = (u16*)(ws + X0);                  // aliases xb+w1t (dead after GEMM1)
  u16* hbuf = (u16*)(ws + X0 + 83886080);
  u16* eo   = (u16*)(ws + X0 + 226492416ull);   // [PADCAP][1024] bf16 (no overlap)
  const size_t REQ_FAST = X0 + 226492416ull;                 // ~216 MiB
  const size_t REQ_EO   = REQ_FAST + 35651584ull;            // ~250 MiB

  const bool fast = (ws_size >= REQ_FAST);
  const bool eoPath = (ws_size >= REQ_EO);

  // zero routing scratch (incl. pad entries of assign_* -> token 0, weight 0)
  hipMemsetAsync(ws, 0, fast ? X0 : 336128, stream);
  if (!eoPath) {
    hipMemsetAsync(d_out, 0, (size_t)out_size * sizeof(float), stream);
  }

  gating_kernel<<<N_TOKENS / 4, 256, 0, stream>>>(x, gate_w, gate_b, counts,
                                                  tok_idx, tok_w, xb);
  finalize_routing<<<1, 1, 0, stream>>>(counts, offsets, out + (out_size - 1));

  if (fast) {
    scatter_kernel<<<N_TOKENS / 256, 256, 0, stream>>>(tok_idx, tok_w, offsets, cursors,
                                                       assign_token, assign_w, tok_pos);
    transpose_cvt_kernel<<<dim3(D_HIDDEN / 64, D_MODEL / 64, N_EXPERTS), 256, 0, stream>>>(
        w1, w1t, D_MODEL, D_HIDDEN);
    gemm1_kernel<<<dim3(ROWT, D_HIDDEN / 256), 256, 0, stream>>>(
        xb, w1t, b1, assign_token, offsets, hbuf);
    transpose_cvt_kernel<<<dim3(D_MODEL / 64, D_HIDDEN / 64, N_EXPERTS), 256, 0, stream>>>(
        w2, w2t, D_HIDDEN, D_MODEL);
    if (eoPath) {
      gemm2_kernel<true><<<dim3(ROWT, D_MODEL / 256), 256, 0, stream>>>(
          hbuf, w2t, b2, assign_token, assign_w, offsets, eo);
      combine_kernel<<<(N_TOKENS * D_MODEL) / 1024, 256, 0, stream>>>(eo, tok_pos, out);
    } else {
      gemm2_kernel<false><<<dim3(ROWT, D_MODEL / 256), 256, 0, stream>>>(
          hbuf, w2t, b2, assign_token, assign_w, offsets, out);
    }
  } else {
    moe_fallback_kernel<<<NASSIGN, 256, 0, stream>>>(x, w1, b1, w2, b2, tok_idx, tok_w, out);
  }
}